// Round 2
// baseline (337.544 us; speedup 1.0000x reference)
//
#include <hip/hip_runtime.h>
#include <stdint.h>
#include <math.h>

#define B_ 16
#define N_ 16
#define H_ 640
#define W_ 640
#define PH_ 300
#define PW_ 300

#define IMG_ELEMS (H_*W_*3)        // 1228800
#define PATCH_ELEMS (PH_*PW_*3)    // 270000

typedef float f32x4 __attribute__((ext_vector_type(4)));

// ---------------- JAX Threefry-2x32-20, bit-exact ----------------
__device__ __forceinline__ uint2 tf2x32(uint32_t k0, uint32_t k1, uint32_t x0, uint32_t x1) {
  uint32_t k2 = k0 ^ k1 ^ 0x1BD11BDAu;
#define TFR(r) x0 += x1; x1 = (x1 << (r)) | (x1 >> (32 - (r))); x1 ^= x0;
  x0 += k0; x1 += k1;
  TFR(13) TFR(15) TFR(26) TFR(6)
  x0 += k1; x1 += k2 + 1u;
  TFR(17) TFR(29) TFR(16) TFR(24)
  x0 += k2; x1 += k0 + 2u;
  TFR(13) TFR(15) TFR(26) TFR(6)
  x0 += k0; x1 += k1 + 3u;
  TFR(17) TFR(29) TFR(16) TFR(24)
  x0 += k1; x1 += k2 + 4u;
  TFR(13) TFR(15) TFR(26) TFR(6)
  x0 += k2; x1 += k0 + 5u;
#undef TFR
  return make_uint2(x0, x1);
}

__device__ __forceinline__ uint32_t rb32(uint32_t k0, uint32_t k1, uint32_t i) {
  uint2 o = tf2x32(k0, k1, 0u, i);
  return o.x ^ o.y;
}

__device__ __forceinline__ float u01f(uint32_t bits) {
  return __uint_as_float((bits >> 9) | 0x3F800000u) - 1.0f;
}

// XLA f32 ErfInv (Giles polynomial) — matches lax.erf_inv
__device__ __forceinline__ float erfinv32(float x) {
  float w = -log1pf(-x * x);
  float p;
  if (w < 5.0f) {
    w = w - 2.5f;
    p = 2.81022636e-08f;
    p = fmaf(p, w, 3.43273939e-07f);
    p = fmaf(p, w, -3.5233877e-06f);
    p = fmaf(p, w, -4.39150654e-06f);
    p = fmaf(p, w, 0.00021858087f);
    p = fmaf(p, w, -0.00125372503f);
    p = fmaf(p, w, -0.00417768164f);
    p = fmaf(p, w, 0.246640727f);
    p = fmaf(p, w, 1.50140941f);
  } else {
    w = sqrtf(w) - 3.0f;
    p = -0.000200214257f;
    p = fmaf(p, w, 0.000100950558f);
    p = fmaf(p, w, 0.00134934322f);
    p = fmaf(p, w, -0.00367342844f);
    p = fmaf(p, w, 0.00573950773f);
    p = fmaf(p, w, -0.0076224613f);
    p = fmaf(p, w, 0.00943887047f);
    p = fmaf(p, w, 1.00167406f);
    p = fmaf(p, w, 2.83297682f);
  }
  return p * x;
}

__device__ __forceinline__ float jnormal(uint32_t bits) {
  float lo = __uint_as_float(0xBF7FFFFFu);  // nextafterf(-1,0)
  float span = 1.0f - lo;                   // rounds to 2.0f, same as XLA
  float u = fmaxf(lo, u01f(bits) * span + lo);
  return 1.4142135623730951f * erfinv32(u);
}

// ---------------- per-(image,box) parameters ----------------
// params[t*16]: 0 y0i, 1 x0i, 2 diagi, 3 phi, 4 c, 5 ca, 6 sa, 7 top,
//               8 bright, 9 300/phi, 10 unused, 11 valid, 12 k2a, 13 k2b
__global__ void setup_kernel(const float* __restrict__ boxes, const float* __restrict__ scale_p,
                             float* __restrict__ params, float* __restrict__ wb) {
  int t = threadIdx.x;
  if (t >= B_*N_) return;
  int b = t >> 4, n = t & 15;
  uint2 kb = tf2x32(0u, 42u, 0u, (uint32_t)b);
  uint2 kw  = tf2x32(kb.x, kb.y, 0u, 0u);
  uint2 kbk = tf2x32(kb.x, kb.y, 0u, 1u);
  uint2 kl  = tf2x32(kb.x, kb.y, 0u, 2u);
  if (n == 0) {
    wb[b*8+0] = jnormal(rb32(kw.x,  kw.y,  0u)) * 0.1f + 0.5f;
    wb[b*8+1] = jnormal(rb32(kw.x,  kw.y,  1u)) * 0.1f + 0.5f;
    wb[b*8+2] = jnormal(rb32(kw.x,  kw.y,  2u)) * 0.1f + 0.5f;
    wb[b*8+3] = jnormal(rb32(kbk.x, kbk.y, 0u)) * 0.01f;
    wb[b*8+4] = jnormal(rb32(kbk.x, kbk.y, 1u)) * 0.01f;
    wb[b*8+5] = jnormal(rb32(kbk.x, kbk.y, 2u)) * 0.01f;
  }
  uint2 kk = tf2x32(kl.x, kl.y, 0u, (uint32_t)n);
  uint2 k1 = tf2x32(kk.x, kk.y, 0u, 0u);
  uint2 k2 = tf2x32(kk.x, kk.y, 0u, 1u);
  uint2 k3 = tf2x32(kk.x, kk.y, 0u, 2u);
  const float MA = (float)(20.0 * 3.14159265358979323846 / 180.0);
  float angle  = fmaxf(-MA,   u01f(rb32(k1.x, k1.y, 0u)) * (MA - (-MA)) + (-MA));
  float bright = fmaxf(-0.3f, u01f(rb32(k3.x, k3.y, 0u)) * (0.3f - (-0.3f)) + (-0.3f));

  const float* bx = boxes + (size_t)t * 4;
  float ymin = bx[0], xmin = bx[1], ymax = bx[2], xmax = bx[3];
  float sc = scale_p[0];
  float h = ymax - ymin, ww = xmax - xmin;
  float longer = fmaxf(h, ww);
  float ps = floorf(longer * sc);
  float diag = fminf(sqrtf(2.0f) * ps, (float)W_);
  float oy = ymin + h * 0.5f;
  float ox = xmin + ww * 0.5f;
  float y0 = fmaxf(oy - diag * 0.5f, 0.0f);
  float x0 = fmaxf(ox - diag * 0.5f, 0.0f);
  if (y0 + diag > (float)H_) y0 = (float)H_ - diag;
  if (x0 + diag > (float)W_) x0 = (float)W_ - diag;
  float y0i = floorf(y0), x0i = floorf(x0);
  float phi = fmaxf(floorf(ps), 1.0f);
  float diagi = floorf(diag);
  float validf = ((phi * phi) > 60.0f) ? 1.0f : 0.0f;
  float c = (diagi - 1.0f) * 0.5f;
  float top = floorf((diagi - phi) * 0.5f);

  float* P = params + t * 16;
  P[0] = y0i; P[1] = x0i; P[2] = diagi; P[3] = phi;
  P[4] = c;
  P[5] = (float)cos((double)angle);   // correctly-rounded f32 cos
  P[6] = (float)sin((double)angle);
  P[7] = top;
  P[8] = bright; P[9] = (float)PH_ / phi; P[10] = 0.0f; P[11] = validf;
  P[12] = __uint_as_float(k2.x); P[13] = __uint_as_float(k2.y); P[14] = 0.0f; P[15] = 0.0f;
}

// ---------------- per-image means (deterministic partials) ----------------
// UNCHANGED summation order — dvals feeds a constant shift and the absmax
// margin is exactly at threshold; do not perturb.
__global__ __launch_bounds__(256) void reduce_kernel(
    const float* __restrict__ images, const float* __restrict__ patch,
    const float* __restrict__ wb, double* __restrict__ partials) {
  int b = blockIdx.y, j = blockIdx.x, t = threadIdx.x;
  const float* img = images + (size_t)b * IMG_ELEMS;
  double s = 0.0;
  for (int i = j * 256 + t; i < IMG_ELEMS; i += 64 * 256) s += (double)img[i];
  float w0 = wb[b*8+0], w1 = wb[b*8+1], w2 = wb[b*8+2];
  float b0 = wb[b*8+3], b1 = wb[b*8+4], b2 = wb[b*8+5];
  double sp = 0.0;
  for (int i = j * 256 + t; i < PATCH_ELEMS; i += 64 * 256) {
    int q = i / 3; int ch = i - q * 3;
    float wv = (ch == 0) ? w0 : ((ch == 1) ? w1 : w2);
    float bv = (ch == 0) ? b0 : ((ch == 1) ? b1 : b2);
    float pv = fminf(fmaxf(wv * patch[i] + bv, -1.0f), 1.0f);
    sp += (double)pv;
  }
  __shared__ double sh[256];
  sh[t] = s; __syncthreads();
  for (int o = 128; o > 0; o >>= 1) { if (t < o) sh[t] += sh[t + o]; __syncthreads(); }
  if (t == 0) partials[((size_t)b * 64 + j) * 2 + 0] = sh[0];
  __syncthreads();
  sh[t] = sp; __syncthreads();
  for (int o = 128; o > 0; o >>= 1) { if (t < o) sh[t] += sh[t + o]; __syncthreads(); }
  if (t == 0) partials[((size_t)b * 64 + j) * 2 + 1] = sh[0];
}

// ---------------- main compose: 4 pixels per thread, float4 I/O ----------------
// Inlined finalize (same serial-64 order as the old finalize_kernel) +
// per-block active-box culling by row range.
__global__ __launch_bounds__(256) void main_kernel(
    const float* __restrict__ images, const float* __restrict__ patch,
    const float* __restrict__ params, const float* __restrict__ wb,
    const double* __restrict__ partials, float* __restrict__ out) {
  __shared__ float sP[N_ * 16];
  __shared__ float sWB[6];
  __shared__ float sD;
  __shared__ int sList[N_];
  __shared__ int sCount;
  __shared__ double sRi[64], sRp[64];

  int b = blockIdx.y;
  int tid = threadIdx.x;
  if (tid < N_ * 16) sP[tid] = params[b * N_ * 16 + tid];
  if (tid < 6) sWB[tid] = wb[b * 8 + tid];
  if (tid < 64) {
    sRi[tid] = partials[((size_t)b * 64 + tid) * 2 + 0];
    sRp[tid] = partials[((size_t)b * 64 + tid) * 2 + 1];
  }
  __syncthreads();
  if (tid == 0) {
    double si = 0.0, sp = 0.0;
    for (int j = 0; j < 64; j++) { si += sRi[j]; sp += sRp[j]; }
    float mi = (float)(si / (double)IMG_ELEMS);
    float mp = (float)(sp / (double)PATCH_ELEMS);
    sD = mi - mp;
    // cull boxes whose row range cannot touch this block's 1024 pixels
    int pblk = blockIdx.x * 1024;
    int ys = pblk / W_;
    int ye = (pblk + 1023) / W_;
    int cnt = 0;
    for (int n = 0; n < N_; n++) {
      const float* P = sP + n * 16;
      if (P[11] == 0.0f) continue;
      float fy0 = P[0];                     // integer-valued y0i
      float fy1 = P[0] + P[2] - 1.0f;       // last covered row
      if (fy1 < (float)ys || fy0 > (float)ye) continue;
      sList[cnt++] = n;                     // ascending n: preserves overwrite order
    }
    sCount = cnt;
  }
  __syncthreads();

  int g = blockIdx.x * 256 + tid;           // pixel-group index
  int p0 = g * 4;                           // W%4==0 -> group never crosses a row
  int y = p0 / W_;
  int x0 = p0 - y * W_;
  size_t base = ((size_t)b * (H_ * W_) + (size_t)p0) * 3;   // float offset, 48B-aligned

  const f32x4* iv = (const f32x4*)(images + base);
  f32x4 q0 = iv[0], q1 = iv[1], q2 = iv[2];
  float orig[12] = {q0.x, q0.y, q0.z, q0.w, q1.x, q1.y, q1.z, q1.w, q2.x, q2.y, q2.z, q2.w};
  float img[12], mk[12];
#pragma unroll
  for (int e = 0; e < 12; e++) { img[e] = orig[e]; mk[e] = 0.0f; }

  float yf = (float)y;
  float dsh = sD;
  int cnt = sCount;
  for (int li = 0; li < cnt; li++) {
    int n = sList[li];
    const float* P = sP + n * 16;
    float diagi = P[2];
    float u = yf - P[0];
    if (!(u >= 0.0f && u < diagi)) continue;      // uniform for the 4 pixels
    float phi = P[3], c = P[4], ca = P[5], sa = P[6], top = P[7], bright = P[8], sph = P[9];
    uint32_t k2a = __float_as_uint(P[12]);
    uint32_t k2b = __float_as_uint(P[13]);
    float t1 = u - c;
    float cct1 = c + ca * t1;      // su = (c + ca*t1) - sa*t2  (same assoc. as before)
    float cst1 = c + sa * t1;      // sv = (c + sa*t1) + ca*t2
#pragma unroll
    for (int j = 0; j < 4; j++) {
      float v = (float)(x0 + j) - P[1];
      if (!(v >= 0.0f && v < diagi)) continue;
      float t2 = v - c;
      float su = cct1 - sa * t2;
      float sv = cst1 + ca * t2;
      float py = su - top;
      float px = sv - top;
      bool vsrc = (py >= 0.0f) && (py <= phi - 1.0f) && (px >= 0.0f) && (px <= phi - 1.0f);
      if (vsrc) {
        float sy = (py + 0.5f) * sph - 0.5f;
        float sx = (px + 0.5f) * sph - 0.5f;
        float fy = floorf(sy), fx = floorf(sx);
        float wy = sy - fy, wxv = sx - fx;
        int iy0 = min(max((int)fy, 0), PH_ - 1);
        int iy1 = min(iy0 + 1, PH_ - 1);
        int ix0 = min(max((int)fx, 0), PW_ - 1);
        int ix1 = min(ix0 + 1, PW_ - 1);
        int o00 = (iy0 * PW_ + ix0) * 3;
        int o01 = (iy0 * PW_ + ix1) * 3;
        int o10 = (iy1 * PW_ + ix0) * 3;
        int o11 = (iy1 * PW_ + ix1) * 3;
        float omwy = 1.0f - wy, omwx = 1.0f - wxv;
        int nbase = (p0 + j) * 3;
#pragma unroll
        for (int ch = 0; ch < 3; ch++) {
          float wv = sWB[ch], bv = sWB[3 + ch];
          float a00 = fminf(fmaxf(wv * patch[o00 + ch] + bv, -1.0f), 1.0f);
          float a01 = fminf(fmaxf(wv * patch[o01 + ch] + bv, -1.0f), 1.0f);
          float a10 = fminf(fmaxf(wv * patch[o10 + ch] + bv, -1.0f), 1.0f);
          float a11 = fminf(fmaxf(wv * patch[o11 + ch] + bv, -1.0f), 1.0f);
          a00 = fminf(fmaxf(a00 + dsh, -1.0f), 1.0f);
          a01 = fminf(fmaxf(a01 + dsh, -1.0f), 1.0f);
          a10 = fminf(fmaxf(a10 + dsh, -1.0f), 1.0f);
          a11 = fminf(fmaxf(a11 + dsh, -1.0f), 1.0f);
          float samp = ((a00 * omwy) * omwx) + ((a01 * omwy) * wxv)
                     + ((a10 * wy) * omwx) + ((a11 * wy) * wxv);
          int i = nbase + ch;
          uint32_t bits = rb32(k2a, k2b, (uint32_t)i);
          float nz = fmaxf(-0.1f, u01f(bits) * (0.1f - (-0.1f)) + (-0.1f));
          float imv = fminf(fmaxf((samp + nz) + bright, -1.0f), 1.0f);
          img[j * 3 + ch] = imv;
          mk[j * 3 + ch] = orig[j * 3 + ch] - imv;
        }
      } else {
        // in square but outside rotated patch: image unchanged, mask = oimg - current bg
#pragma unroll
        for (int ch = 0; ch < 3; ch++) mk[j * 3 + ch] = orig[j * 3 + ch] - img[j * 3 + ch];
      }
    }
  }

  size_t moff = (size_t)B_ * (H_ * W_) * 3;
  f32x4* ov = (f32x4*)(out + base);
  f32x4* mv = (f32x4*)(out + moff + base);
  f32x4 o0 = {img[0], img[1], img[2],  img[3]};
  f32x4 o1 = {img[4], img[5], img[6],  img[7]};
  f32x4 o2 = {img[8], img[9], img[10], img[11]};
  f32x4 m0 = {mk[0],  mk[1],  mk[2],   mk[3]};
  f32x4 m1 = {mk[4],  mk[5],  mk[6],   mk[7]};
  f32x4 m2 = {mk[8],  mk[9],  mk[10],  mk[11]};
  __builtin_nontemporal_store(o0, ov + 0);
  __builtin_nontemporal_store(o1, ov + 1);
  __builtin_nontemporal_store(o2, ov + 2);
  __builtin_nontemporal_store(m0, mv + 0);
  __builtin_nontemporal_store(m1, mv + 1);
  __builtin_nontemporal_store(m2, mv + 2);
}

extern "C" void kernel_launch(void* const* d_in, const int* in_sizes, int n_in,
                              void* d_out, int out_size, void* d_ws, size_t ws_size,
                              hipStream_t stream) {
  const float* boxes  = (const float*)d_in[0];
  const float* images = (const float*)d_in[1];
  const float* patch  = (const float*)d_in[2];
  const float* scale  = (const float*)d_in[3];
  float* out = (float*)d_out;

  // ws layout: [0,16384) box params (256*16 f32); [16384,16896) per-image w/b (16*8 f32);
  //            [20480,36864) partial sums (16*64*2 f64)
  float* params = (float*)d_ws;
  float* wb     = params + B_ * N_ * 16;
  double* partials = (double*)((char*)d_ws + 20480);

  setup_kernel<<<1, 256, 0, stream>>>(boxes, scale, params, wb);
  reduce_kernel<<<dim3(64, B_), 256, 0, stream>>>(images, patch, wb, partials);
  main_kernel<<<dim3((H_ * W_) / 1024, B_), 256, 0, stream>>>(images, patch, params, wb, partials, out);
}

// Round 3
// 294.716 us; speedup vs baseline: 1.1453x; 1.1453x over previous
//
#include <hip/hip_runtime.h>
#include <stdint.h>
#include <math.h>

#define B_ 16
#define N_ 16
#define H_ 640
#define W_ 640
#define PH_ 300
#define PW_ 300

#define IMG_ELEMS (H_*W_*3)        // 1228800
#define PATCH_ELEMS (PH_*PW_*3)    // 270000

// ---------------- JAX Threefry-2x32-20, bit-exact ----------------
__device__ __forceinline__ uint2 tf2x32(uint32_t k0, uint32_t k1, uint32_t x0, uint32_t x1) {
  uint32_t k2 = k0 ^ k1 ^ 0x1BD11BDAu;
#define TFR(r) x0 += x1; x1 = (x1 << (r)) | (x1 >> (32 - (r))); x1 ^= x0;
  x0 += k0; x1 += k1;
  TFR(13) TFR(15) TFR(26) TFR(6)
  x0 += k1; x1 += k2 + 1u;
  TFR(17) TFR(29) TFR(16) TFR(24)
  x0 += k2; x1 += k0 + 2u;
  TFR(13) TFR(15) TFR(26) TFR(6)
  x0 += k0; x1 += k1 + 3u;
  TFR(17) TFR(29) TFR(16) TFR(24)
  x0 += k1; x1 += k2 + 4u;
  TFR(13) TFR(15) TFR(26) TFR(6)
  x0 += k2; x1 += k0 + 5u;
#undef TFR
  return make_uint2(x0, x1);
}

__device__ __forceinline__ uint32_t rb32(uint32_t k0, uint32_t k1, uint32_t i) {
  uint2 o = tf2x32(k0, k1, 0u, i);
  return o.x ^ o.y;
}

__device__ __forceinline__ float u01f(uint32_t bits) {
  return __uint_as_float((bits >> 9) | 0x3F800000u) - 1.0f;
}

// XLA f32 ErfInv (Giles polynomial) — matches lax.erf_inv
__device__ __forceinline__ float erfinv32(float x) {
  float w = -log1pf(-x * x);
  float p;
  if (w < 5.0f) {
    w = w - 2.5f;
    p = 2.81022636e-08f;
    p = fmaf(p, w, 3.43273939e-07f);
    p = fmaf(p, w, -3.5233877e-06f);
    p = fmaf(p, w, -4.39150654e-06f);
    p = fmaf(p, w, 0.00021858087f);
    p = fmaf(p, w, -0.00125372503f);
    p = fmaf(p, w, -0.00417768164f);
    p = fmaf(p, w, 0.246640727f);
    p = fmaf(p, w, 1.50140941f);
  } else {
    w = sqrtf(w) - 3.0f;
    p = -0.000200214257f;
    p = fmaf(p, w, 0.000100950558f);
    p = fmaf(p, w, 0.00134934322f);
    p = fmaf(p, w, -0.00367342844f);
    p = fmaf(p, w, 0.00573950773f);
    p = fmaf(p, w, -0.0076224613f);
    p = fmaf(p, w, 0.00943887047f);
    p = fmaf(p, w, 1.00167406f);
    p = fmaf(p, w, 2.83297682f);
  }
  return p * x;
}

__device__ __forceinline__ float jnormal(uint32_t bits) {
  float lo = __uint_as_float(0xBF7FFFFFu);  // nextafterf(-1,0)
  float span = 1.0f - lo;                   // rounds to 2.0f, same as XLA
  float u = fmaxf(lo, u01f(bits) * span + lo);
  return 1.4142135623730951f * erfinv32(u);
}

// ---------------- per-(image,box) parameters ----------------
// params[t*16]: 0 y0i, 1 x0i, 2 diagi, 3 phi, 4 c, 5 ca, 6 sa, 7 top,
//               8 bright, 9 300/phi, 10 unused, 11 valid, 12 k2a, 13 k2b
__global__ void setup_kernel(const float* __restrict__ boxes, const float* __restrict__ scale_p,
                             float* __restrict__ params, float* __restrict__ wb) {
  int t = threadIdx.x;
  if (t >= B_*N_) return;
  int b = t >> 4, n = t & 15;
  uint2 kb = tf2x32(0u, 42u, 0u, (uint32_t)b);
  uint2 kw  = tf2x32(kb.x, kb.y, 0u, 0u);
  uint2 kbk = tf2x32(kb.x, kb.y, 0u, 1u);
  uint2 kl  = tf2x32(kb.x, kb.y, 0u, 2u);
  if (n == 0) {
    wb[b*8+0] = jnormal(rb32(kw.x,  kw.y,  0u)) * 0.1f + 0.5f;
    wb[b*8+1] = jnormal(rb32(kw.x,  kw.y,  1u)) * 0.1f + 0.5f;
    wb[b*8+2] = jnormal(rb32(kw.x,  kw.y,  2u)) * 0.1f + 0.5f;
    wb[b*8+3] = jnormal(rb32(kbk.x, kbk.y, 0u)) * 0.01f;
    wb[b*8+4] = jnormal(rb32(kbk.x, kbk.y, 1u)) * 0.01f;
    wb[b*8+5] = jnormal(rb32(kbk.x, kbk.y, 2u)) * 0.01f;
  }
  uint2 kk = tf2x32(kl.x, kl.y, 0u, (uint32_t)n);
  uint2 k1 = tf2x32(kk.x, kk.y, 0u, 0u);
  uint2 k2 = tf2x32(kk.x, kk.y, 0u, 1u);
  uint2 k3 = tf2x32(kk.x, kk.y, 0u, 2u);
  const float MA = (float)(20.0 * 3.14159265358979323846 / 180.0);
  float angle  = fmaxf(-MA,   u01f(rb32(k1.x, k1.y, 0u)) * (MA - (-MA)) + (-MA));
  float bright = fmaxf(-0.3f, u01f(rb32(k3.x, k3.y, 0u)) * (0.3f - (-0.3f)) + (-0.3f));

  const float* bx = boxes + (size_t)t * 4;
  float ymin = bx[0], xmin = bx[1], ymax = bx[2], xmax = bx[3];
  float sc = scale_p[0];
  float h = ymax - ymin, ww = xmax - xmin;
  float longer = fmaxf(h, ww);
  float ps = floorf(longer * sc);
  float diag = fminf(sqrtf(2.0f) * ps, (float)W_);
  float oy = ymin + h * 0.5f;
  float ox = xmin + ww * 0.5f;
  float y0 = fmaxf(oy - diag * 0.5f, 0.0f);
  float x0 = fmaxf(ox - diag * 0.5f, 0.0f);
  if (y0 + diag > (float)H_) y0 = (float)H_ - diag;
  if (x0 + diag > (float)W_) x0 = (float)W_ - diag;
  float y0i = floorf(y0), x0i = floorf(x0);
  float phi = fmaxf(floorf(ps), 1.0f);
  float diagi = floorf(diag);
  float validf = ((phi * phi) > 60.0f) ? 1.0f : 0.0f;
  float c = (diagi - 1.0f) * 0.5f;
  float top = floorf((diagi - phi) * 0.5f);

  float* P = params + t * 16;
  P[0] = y0i; P[1] = x0i; P[2] = diagi; P[3] = phi;
  P[4] = c;
  P[5] = (float)cos((double)angle);   // correctly-rounded f32 cos
  P[6] = (float)sin((double)angle);
  P[7] = top;
  P[8] = bright; P[9] = (float)PH_ / phi; P[10] = 0.0f; P[11] = validf;
  P[12] = __uint_as_float(k2.x); P[13] = __uint_as_float(k2.y); P[14] = 0.0f; P[15] = 0.0f;
}

// ---------------- per-image means (deterministic partials) ----------------
// UNCHANGED summation order — dvals feeds a constant shift; do not perturb.
__global__ __launch_bounds__(256) void reduce_kernel(
    const float* __restrict__ images, const float* __restrict__ patch,
    const float* __restrict__ wb, double* __restrict__ partials) {
  int b = blockIdx.y, j = blockIdx.x, t = threadIdx.x;
  const float* img = images + (size_t)b * IMG_ELEMS;
  double s = 0.0;
  for (int i = j * 256 + t; i < IMG_ELEMS; i += 64 * 256) s += (double)img[i];
  float w0 = wb[b*8+0], w1 = wb[b*8+1], w2 = wb[b*8+2];
  float b0 = wb[b*8+3], b1 = wb[b*8+4], b2 = wb[b*8+5];
  double sp = 0.0;
  for (int i = j * 256 + t; i < PATCH_ELEMS; i += 64 * 256) {
    int q = i / 3; int ch = i - q * 3;
    float wv = (ch == 0) ? w0 : ((ch == 1) ? w1 : w2);
    float bv = (ch == 0) ? b0 : ((ch == 1) ? b1 : b2);
    float pv = fminf(fmaxf(wv * patch[i] + bv, -1.0f), 1.0f);
    sp += (double)pv;
  }
  __shared__ double sh[256];
  sh[t] = s; __syncthreads();
  for (int o = 128; o > 0; o >>= 1) { if (t < o) sh[t] += sh[t + o]; __syncthreads(); }
  if (t == 0) partials[((size_t)b * 64 + j) * 2 + 0] = sh[0];
  __syncthreads();
  sh[t] = sp; __syncthreads();
  for (int o = 128; o > 0; o >>= 1) { if (t < o) sh[t] += sh[t + o]; __syncthreads(); }
  if (t == 0) partials[((size_t)b * 64 + j) * 2 + 1] = sh[0];
}

// ---------------- main compose: lane-major 4 px/thread ----------------
// Wave w covers 256 consecutive pixels; lane l, sub j -> pixel span + j*64 + l.
// Each 64-px chunk sits in ONE row (640 % 64 == 0) -> row test is wave-uniform.
// Inlined finalize (same serial-64 order) + per-block box culling by row range.
__global__ __launch_bounds__(256) void main_kernel(
    const float* __restrict__ images, const float* __restrict__ patch,
    const float* __restrict__ params, const float* __restrict__ wb,
    const double* __restrict__ partials, float* __restrict__ out) {
  __shared__ float sP[N_ * 16];
  __shared__ float sWB[6];
  __shared__ float sD;
  __shared__ int sList[N_];
  __shared__ int sCount;
  __shared__ double sRi[64], sRp[64];

  int b = blockIdx.y;
  int tid = threadIdx.x;
  if (tid < N_ * 16) sP[tid] = params[b * N_ * 16 + tid];
  if (tid < 6) sWB[tid] = wb[b * 8 + tid];
  if (tid < 64) {
    sRi[tid] = partials[((size_t)b * 64 + tid) * 2 + 0];
    sRp[tid] = partials[((size_t)b * 64 + tid) * 2 + 1];
  }
  __syncthreads();
  if (tid == 0) {
    double si = 0.0, sp = 0.0;
    for (int j = 0; j < 64; j++) { si += sRi[j]; sp += sRp[j]; }
    float mi = (float)(si / (double)IMG_ELEMS);
    float mp = (float)(sp / (double)PATCH_ELEMS);
    sD = mi - mp;
    // cull boxes whose row range cannot touch this block's 1024 pixels
    int pblk = blockIdx.x * 1024;
    int ys = pblk / W_;
    int ye = (pblk + 1023) / W_;
    int cnt = 0;
    for (int n = 0; n < N_; n++) {
      const float* P = sP + n * 16;
      if (P[11] == 0.0f) continue;
      float fy0 = P[0];                     // integer-valued y0i
      float fy1 = P[0] + P[2] - 1.0f;       // last covered row
      if (fy1 < (float)ys || fy0 > (float)ye) continue;
      sList[cnt++] = n;                     // ascending n: preserves overwrite order
    }
    sCount = cnt;
  }
  __syncthreads();

  int lane = tid & 63;
  int wv   = tid >> 6;
  int span = blockIdx.x * 1024 + wv * 256;      // wave's 256-px span
  size_t ibase = (size_t)b * (H_ * W_) * 3;

  // per-j pixel coords (all static-indexed; j fully unrolled everywhere)
  int   pj[4];  float yfj[4], xfj[4];
#pragma unroll
  for (int j = 0; j < 4; j++) {
    int p = span + j * 64 + lane;
    int chunk = span + j * 64;                  // 64-aligned, single row
    int y = chunk / W_;
    pj[j]  = p;
    yfj[j] = (float)y;
    xfj[j] = (float)(chunk - y * W_ + lane);
  }

  float orig[12], img[12], mk[12];
#pragma unroll
  for (int j = 0; j < 4; j++) {
    const float* src = images + ibase + (size_t)pj[j] * 3;
    orig[j*3+0] = src[0]; orig[j*3+1] = src[1]; orig[j*3+2] = src[2];
  }
#pragma unroll
  for (int e = 0; e < 12; e++) { img[e] = orig[e]; mk[e] = 0.0f; }

  float dsh = sD;
  int cnt = sCount;
  for (int li = 0; li < cnt; li++) {
    const float* P = sP + sList[li] * 16;
    float P0 = P[0], P1 = P[1], diagi = P[2];
    float phi = P[3], c = P[4], ca = P[5], sa = P[6], top = P[7], bright = P[8], sph = P[9];
    uint32_t k2a = __float_as_uint(P[12]);
    uint32_t k2b = __float_as_uint(P[13]);
#pragma unroll
    for (int j = 0; j < 4; j++) {
      float u = yfj[j] - P0;
      if (!(u >= 0.0f && u < diagi)) continue;    // wave-uniform row test
      float v = xfj[j] - P1;
      if (!(v >= 0.0f && v < diagi)) continue;    // per-lane col test
      float t1 = u - c, t2 = v - c;
      float su = (c + ca * t1) - sa * t2;         // same association as before
      float sv = (c + sa * t1) + ca * t2;
      float py = su - top;
      float px = sv - top;
      bool vsrc = (py >= 0.0f) && (py <= phi - 1.0f) && (px >= 0.0f) && (px <= phi - 1.0f);
      if (vsrc) {
        float sy = (py + 0.5f) * sph - 0.5f;
        float sx = (px + 0.5f) * sph - 0.5f;
        float fy = floorf(sy), fx = floorf(sx);
        float wy = sy - fy, wxv = sx - fx;
        int iy0 = min(max((int)fy, 0), PH_ - 1);
        int iy1 = min(iy0 + 1, PH_ - 1);
        int ix0 = min(max((int)fx, 0), PW_ - 1);
        int ix1 = min(ix0 + 1, PW_ - 1);
        int o00 = (iy0 * PW_ + ix0) * 3;
        int o01 = (iy0 * PW_ + ix1) * 3;
        int o10 = (iy1 * PW_ + ix0) * 3;
        int o11 = (iy1 * PW_ + ix1) * 3;
        float omwy = 1.0f - wy, omwx = 1.0f - wxv;
        int nbase = pj[j] * 3;
#pragma unroll
        for (int ch = 0; ch < 3; ch++) {
          float wv2 = sWB[ch], bv = sWB[3 + ch];
          float a00 = fminf(fmaxf(wv2 * patch[o00 + ch] + bv, -1.0f), 1.0f);
          float a01 = fminf(fmaxf(wv2 * patch[o01 + ch] + bv, -1.0f), 1.0f);
          float a10 = fminf(fmaxf(wv2 * patch[o10 + ch] + bv, -1.0f), 1.0f);
          float a11 = fminf(fmaxf(wv2 * patch[o11 + ch] + bv, -1.0f), 1.0f);
          a00 = fminf(fmaxf(a00 + dsh, -1.0f), 1.0f);
          a01 = fminf(fmaxf(a01 + dsh, -1.0f), 1.0f);
          a10 = fminf(fmaxf(a10 + dsh, -1.0f), 1.0f);
          a11 = fminf(fmaxf(a11 + dsh, -1.0f), 1.0f);
          float samp = ((a00 * omwy) * omwx) + ((a01 * omwy) * wxv)
                     + ((a10 * wy) * omwx) + ((a11 * wy) * wxv);
          int i = nbase + ch;
          uint32_t bits = rb32(k2a, k2b, (uint32_t)i);
          float nz = fmaxf(-0.1f, u01f(bits) * (0.1f - (-0.1f)) + (-0.1f));
          float imv = fminf(fmaxf((samp + nz) + bright, -1.0f), 1.0f);
          img[j * 3 + ch] = imv;
          mk[j * 3 + ch] = orig[j * 3 + ch] - imv;
        }
      } else {
        // in square but outside rotated patch: image unchanged, mask = oimg - current bg
#pragma unroll
        for (int ch = 0; ch < 3; ch++) mk[j * 3 + ch] = orig[j * 3 + ch] - img[j * 3 + ch];
      }
    }
  }

  size_t moff = (size_t)B_ * (H_ * W_) * 3;
#pragma unroll
  for (int j = 0; j < 4; j++) {
    float* od = out + ibase + (size_t)pj[j] * 3;
    float* md = od + moff;
#pragma unroll
    for (int ch = 0; ch < 3; ch++) {
      __builtin_nontemporal_store(img[j*3+ch], od + ch);
      __builtin_nontemporal_store(mk[j*3+ch],  md + ch);
    }
  }
}

extern "C" void kernel_launch(void* const* d_in, const int* in_sizes, int n_in,
                              void* d_out, int out_size, void* d_ws, size_t ws_size,
                              hipStream_t stream) {
  const float* boxes  = (const float*)d_in[0];
  const float* images = (const float*)d_in[1];
  const float* patch  = (const float*)d_in[2];
  const float* scale  = (const float*)d_in[3];
  float* out = (float*)d_out;

  // ws layout: [0,16384) box params (256*16 f32); [16384,16896) per-image w/b (16*8 f32);
  //            [20480,36864) partial sums (16*64*2 f64)
  float* params = (float*)d_ws;
  float* wb     = params + B_ * N_ * 16;
  double* partials = (double*)((char*)d_ws + 20480);

  setup_kernel<<<1, 256, 0, stream>>>(boxes, scale, params, wb);
  reduce_kernel<<<dim3(64, B_), 256, 0, stream>>>(images, patch, wb, partials);
  main_kernel<<<dim3((H_ * W_) / 1024, B_), 256, 0, stream>>>(images, patch, params, wb, partials, out);
}